// Round 1
// baseline (451.768 us; speedup 1.0000x reference)
//
#include <hip/hip_runtime.h>

// ---------------------------------------------------------------------------
// LayerStacks (NNUE-style) on MI355X.
//   h0 = clamp01( x @ (w0[b]+w_fact)^T + b0[b] )   // 1024 -> 32, bf16 MFMA
//   h1 = clamp01( h0 @ w1[b]^T + b1[b] )           // 32 -> 32,  fp32 VALU
//   out = h1 @ w2[b]^T + b2[b]                     // 32 -> 1,   fp32 VALU
// R4: NO SORT. R2/R3 showed sorted-row gather is DRAM page-activate bound
// (~0.8-2 TB/s). MFMA is so cheap (34 GF total ~ 14us) that computing h0 for
// ALL 8 buckets per row and selecting afterwards is faster: each block reads
// 32 CONSECUTIVE rows (128 KB fully sequential stream -> full HBM BW), each
// wave MFMAs 2 buckets over full K, epilogue selects per-row bucket.
// Weights (512 KB bf16) are L2-resident; ~1 GB L2 traffic overlaps HBM.
// ---------------------------------------------------------------------------

#define B_ROWS 65536
#define LK     1024       // 2*L1
#define TILE   32
#define NBLK   (B_ROWS / TILE)   // 2048, exact
#define SROW   2056       // LDS row stride in bytes (1028 bf16): 2-way-free banks

// ws layout (bytes):
//   [0, 524288) : wB bf16 B-frags of (w0+w_fact): per bucket 4096 uint4;
//                 frag idx c*64+l holds W[bkt*32 + (l&31)][16c + 8*(l>>5) .. +8]

typedef short  short8  __attribute__((ext_vector_type(8)));
typedef float  f32x16  __attribute__((ext_vector_type(16)));

__device__ __forceinline__ unsigned pkbf(float a, float b) {
    // round-to-nearest-even fp32 -> bf16, packed pair
    unsigned ua = __float_as_uint(a), ub = __float_as_uint(b);
    ua = (ua + 0x7FFFu + ((ua >> 16) & 1u)) >> 16;
    ub = (ub + 0x7FFFu + ((ub >> 16) & 1u)) >> 16;
    return (ua & 0xFFFFu) | (ub << 16);
}

// ls_indices may be int32 or int64. If int64, the high words (odd int32
// slots) of the first 64 elements are all zero (values 0..7). Deterministic.
__device__ __forceinline__ bool detect_i64(const int* p) {
    int acc = 0;
#pragma unroll
    for (int i = 0; i < 64; ++i) acc |= p[2 * i + 1];
    return acc == 0;
}

__device__ __forceinline__ int load_bucket(const int* p, int r, bool i64) {
    return (i64 ? p[2 * r] : p[r]) & 7;
}

// --- K1: weight prep only ---------------------------------------------------
// 32 blocks x 1024 thr: build bf16 B-fragments of (w0+w_fact). 1 frag/thread.
__global__ __launch_bounds__(1024) void k_prep(
    const float* __restrict__ w0, const float* __restrict__ wf,
    uint4* __restrict__ wB)
{
    int f = blockIdx.x * 1024 + threadIdx.x;   // 32768 frags
    int b   = f >> 12;
    int i12 = f & 4095;
    int kc  = i12 >> 8;
    int i8  = i12 & 255;
    int n   = i8 & 31;
    int khi = i8 >> 5;
    int k = kc * 64 + khi * 8;                 // == c*16 + 8*(lane>>5)
    const float* p0 = w0 + (size_t)(b * 32 + n) * LK + k;
    const float* pf = wf + (size_t)n * LK + k;
    float v[8];
#pragma unroll
    for (int j = 0; j < 8; ++j) v[j] = p0[j] + pf[j];
    uint4 o;
    o.x = pkbf(v[0], v[1]); o.y = pkbf(v[2], v[3]);
    o.z = pkbf(v[4], v[5]); o.w = pkbf(v[6], v[7]);
    wB[f] = o;
}

// --- K2: main fused kernel ---------------------------------------------------
// Block = 256 thr = 4 waves; tile = 32 CONSECUTIVE rows, full K=1024 in LDS
// (bf16, row-major, stride SROW). Staging reads are a single sequential
// 128 KB span. Wave wv computes buckets {2wv, 2wv+1} over full K (A-frag
// shared between the two MFMAs). Epilogue: wave owning row's bucket writes
// that row's 32 h0 values; layers 1+2 use per-row bucket weights from L2.
__global__ __launch_bounds__(256, 2) void k_main(
    const float* __restrict__ x, const int* __restrict__ idx,
    const uint4* __restrict__ wB, const float* __restrict__ b0,
    const float* __restrict__ w1, const float* __restrict__ b1,
    const float* __restrict__ w2, const float* __restrict__ b2,
    float* __restrict__ out)
{
    __shared__ __align__(16) unsigned char smem[TILE * SROW];  // 65792 B
    __shared__ float hb[TILE * 36];                            // h0, padded
    __shared__ int   bkt_s[TILE];

    int row0 = blockIdx.x * TILE;
    int t    = threadIdx.x;
    int lane = t & 63;
    int wv   = t >> 6;

    // per-row buckets (L2-cached after first block; tiny)
    if (t < TILE) {
        bool i64 = detect_i64(idx);
        bkt_s[t] = load_bucket(idx, row0 + t, i64);
    }

    // ---- stage 32 consecutive rows; row j = 4 KB contiguous; whole block's
    //      read = one 128 KB sequential span. thread t takes float4 #t.
#pragma unroll
    for (int j0 = 0; j0 < 32; j0 += 8) {
        float4 v[8];
#pragma unroll
        for (int jj = 0; jj < 8; ++jj)
            v[jj] = ((const float4*)(x + (size_t)(row0 + j0 + jj) * LK))[t];
#pragma unroll
        for (int jj = 0; jj < 8; ++jj) {
            uint2 o;
            o.x = pkbf(v[jj].x, v[jj].y);
            o.y = pkbf(v[jj].z, v[jj].w);
            *(uint2*)(smem + (j0 + jj) * SROW + t * 8) = o;  // ds_write_b64
        }
    }
    __syncthreads();

    // ---- MFMA: wave wv computes buckets bb0=2wv, bb1=2wv+1 over full K.
    const uint4* wB0 = wB + (size_t)(2 * wv) * 4096;
    const uint4* wB1 = wB + (size_t)(2 * wv + 1) * 4096;
    const unsigned char* Abase = smem + (size_t)(lane & 31) * SROW + 16 * (lane >> 5);

    f32x16 acc0, acc1;
#pragma unroll
    for (int i = 0; i < 16; ++i) { acc0[i] = 0.0f; acc1[i] = 0.0f; }

    union UA { uint2 h[2]; short8 s; };
    union UB { uint4 u;    short8 s; };
#pragma unroll 4
    for (int c = 0; c < 64; ++c) {
        UA ua;
        ua.h[0] = *(const uint2*)(Abase + 32 * c);       // ds_read_b64 x2,
        ua.h[1] = *(const uint2*)(Abase + 32 * c + 8);   // 2-way aliasing = free
        UB ub0, ub1;
        ub0.u = wB0[c * 64 + lane];                      // L2-resident weights
        ub1.u = wB1[c * 64 + lane];
        acc0 = __builtin_amdgcn_mfma_f32_32x32x16_bf16(ua.s, ub0.s, acc0, 0, 0, 0);
        acc1 = __builtin_amdgcn_mfma_f32_32x32x16_bf16(ua.s, ub1.s, acc1, 0, 0, 0);
    }

    // ---- select per-row bucket: C elem (reg i, lane l) is
    //      m = (i&3)+8*(i>>2)+4*(l>>5), n = l&31
    int bb0 = 2 * wv, bb1 = 2 * wv + 1;
#pragma unroll
    for (int i = 0; i < 16; ++i) {
        int m = (i & 3) + 8 * (i >> 2) + 4 * (lane >> 5);
        int n = lane & 31;
        int mb = bkt_s[m];
        if (mb == bb0 || mb == bb1) {
            float s = (mb == bb0) ? acc0[i] : acc1[i];
            float h = s + b0[mb * 32 + n];
            hb[m * 36 + n] = fminf(fmaxf(h, 0.0f), 1.0f);
        }
    }
    __syncthreads();

    // ---- layers 1+2 (fp32), threads 0..63: pair (2r,2r+1) splits 32 outputs
    if (t < 64) {
        int r = t >> 1, half = t & 1;
        int bkt = bkt_s[r];
        const float4* hr = (const float4*)(hb + r * 36);
        float4 ha[8];
#pragma unroll
        for (int q = 0; q < 8; ++q) ha[q] = hr[q];
        const float* w1b = w1 + (size_t)bkt * 1024;
        const float* b1b = b1 + bkt * 32;
        const float* w2b = w2 + bkt * 32;
        float partial = 0.0f;
#pragma unroll
        for (int jj = 0; jj < 16; ++jj) {
            int j2 = half * 16 + jj;
            const float4* wr = (const float4*)&w1b[j2 * 32];
            float s = b1b[j2];
#pragma unroll
            for (int q = 0; q < 8; ++q) {
                float4 w4 = wr[q];
                s += ha[q].x * w4.x + ha[q].y * w4.y + ha[q].z * w4.z + ha[q].w * w4.w;
            }
            s = fminf(fmaxf(s, 0.0f), 1.0f);
            partial += s * w2b[j2];
        }
        partial += __shfl_xor(partial, 1);
        if (half == 0) out[row0 + r] = partial + b2[bkt];
    }
}

// ---------------------------------------------------------------------------
extern "C" void kernel_launch(void* const* d_in, const int* in_sizes, int n_in,
                              void* d_out, int out_size, void* d_ws, size_t ws_size,
                              hipStream_t stream) {
    const float* x   = (const float*)d_in[0];
    const int*   lsi = (const int*)  d_in[1];
    const float* wf  = (const float*)d_in[2];
    const float* w0  = (const float*)d_in[3];
    const float* b0  = (const float*)d_in[4];
    const float* w1  = (const float*)d_in[5];
    const float* b1  = (const float*)d_in[6];
    const float* w2  = (const float*)d_in[7];
    const float* b2  = (const float*)d_in[8];
    float* out = (float*)d_out;

    uint4* wB = (uint4*)d_ws;

    k_prep<<<32, 1024, 0, stream>>>(w0, wf, wB);
    k_main<<<NBLK, 256, 0, stream>>>(x, lsi, wB, b0, w1, b1, w2, b2, out);
}